// Round 5
// baseline (355.450 us; speedup 1.0000x reference)
//
#include <hip/hip_runtime.h>

// LoRA forward: out = x @ (A @ B * scale)  ==  ((x @ A) * scale) @ B
// x: [4, 2048, 4096] fp32 -> 8192 rows; A: [4096, 8]; B: [8, 4096]; out: [8192, 4096]
//
// R5 post-mortem: R1 (86us) and R5 (109us) are VMEM-ISSUE bound, not HBM
// bound: 83-90% of VMEM instructions are At/B cache re-reads (8 per 1 KB of
// fresh x), each 64-lane dwordx4 spanning 16 lines through the per-CU TA/TCP.
// HBM 23%, VALU 12%, Occ 31% - every pipe idle, issue path saturated.
// R6: eliminate At/B VMEM traffic.
//  - At staged in LDS (64 KB halves, in-block transpose from CONTIGUOUS A
//    region -> transpose dispatch deleted). Phase-1 A reads ride the DS pipe.
//  - Block = 16 waves x 16 rows. After butterfly + tiny t-exchange in LDS,
//    wave w owns column quads [w*64+lane]: loads its B slice ONCE (8 loads,
//    32 VGPR) and reuses it across all 16 rows.
//  - VMEM per wave: ~320 -> ~48; x-stream + out-stream dominate -> HBM floor.
//  - launch_bounds(1024,8): VGPR<=64 -> 2 blocks/CU; LDS 64.5 KB -> fits 2.

#define DIM        4096
#define DIM4       1024        // float4 quads per row
#define RANK       8
#define LORA_SCALE 2.0f
#define BLOCK      1024
#define WAVES      16
#define RPB        16          // rows per block (1 per wave)
#define HALF_COLS  2048        // scalar columns per LDS half
#define HALF_Q     512         // float4 quads per half per rank-row

typedef float f32x4 __attribute__((ext_vector_type(4)));

__global__ __launch_bounds__(BLOCK, 8) void lora_fused_kernel(
    const float* __restrict__ x,
    const float* __restrict__ A,
    const float* __restrict__ B,
    float* __restrict__ out)
{
    __shared__ float sAt[RANK * HALF_COLS];   // 64 KiB: transposed half of A
    __shared__ float tAll[RPB * RANK];        // 512 B: per-row (x@A)*scale

    const int tid  = threadIdx.x;
    const int wave = tid >> 6;
    const int lane = tid & 63;
    const size_t row0 = (size_t)blockIdx.x * RPB;
    const size_t row  = row0 + wave;          // this wave's x-row

    const float4* __restrict__ A4 = (const float4*)A;   // 8192 quads total
    const float4* __restrict__ B4 = (const float4*)B;
    const float4* __restrict__ xr = (const float4*)x + row * DIM4;
    const float4* sAt4 = (const float4*)sAt;

    // ---- Phase 1: acc[r] = sum_i x[row][i] * A[i][r], in two column halves ----
    float acc[RANK];
#pragma unroll
    for (int r = 0; r < RANK; ++r) acc[r] = 0.f;

    for (int h = 0; h < 2; ++h) {
        if (h) __syncthreads();   // half-0 compute done before overwriting sAt
        // Stage: transpose A rows [h*2048, h*2048+2048) (a CONTIGUOUS 64 KB
        // region of A) into sAt[r][il]. Quad j of A = (i = j>>1, r0 = (j&1)*4).
        // Per-instr LDS writes: 32 consecutive floats in 2 rank-rows = 2-way.
#pragma unroll
        for (int q = 0; q < 4; ++q) {
            const int idx = tid + q * BLOCK;           // 0..4095
            const float4 v = A4[h * 4096 + idx];       // coalesced
            const int il = idx >> 1;                   // local column 0..2047
            const int rq = (idx & 1) * 4;
            sAt[(rq + 0) * HALF_COLS + il] = v.x;
            sAt[(rq + 1) * HALF_COLS + il] = v.y;
            sAt[(rq + 2) * HALF_COLS + il] = v.z;
            sAt[(rq + 3) * HALF_COLS + il] = v.w;
        }
        __syncthreads();

        // Compute this half: 8 x-quads per lane, batched 4 for in-flight depth
#pragma unroll
        for (int kb = 0; kb < 2; ++kb) {
            float4 xq[4];
#pragma unroll
            for (int j = 0; j < 4; ++j)
                xq[j] = xr[h * HALF_Q + (kb * 4 + j) * 64 + lane];
#pragma unroll
            for (int j = 0; j < 4; ++j) {
                const int il4 = (kb * 4 + j) * 64 + lane;   // 0..511
#pragma unroll
                for (int r = 0; r < RANK; ++r) {
                    const float4 a = sAt4[r * HALF_Q + il4]; // ds_read_b128
                    acc[r] += xq[j].x * a.x + xq[j].y * a.y
                            + xq[j].z * a.z + xq[j].w * a.w;
                }
            }
        }
    }

    // ---- Phase 2: butterfly reduce (wave-local), deposit t into LDS ----
#pragma unroll
    for (int r = 0; r < RANK; ++r) {
        float v = acc[r];
#pragma unroll
        for (int off = 1; off < 64; off <<= 1)
            v += __shfl_xor(v, off, 64);
        acc[r] = v * LORA_SCALE;
    }
    if (lane < RANK) tAll[wave * RANK + lane] = acc[lane];
    __syncthreads();

    // ---- Phase 3: wave w owns column quads i4c = w*64+lane; B slice in regs ----
    {
        const int i4c = wave * 64 + lane;
        float4 b[RANK];
#pragma unroll
        for (int r = 0; r < RANK; ++r)
            b[r] = B4[r * DIM4 + i4c];                 // once per wave, coalesced
        f32x4* __restrict__ out4 = (f32x4*)out;
#pragma unroll 4
        for (int m = 0; m < RPB; ++m) {
            const float* tv = &tAll[m * RANK];         // uniform -> LDS broadcast
            float4 o;
            o.x = tv[0] * b[0].x; o.y = tv[0] * b[0].y;
            o.z = tv[0] * b[0].z; o.w = tv[0] * b[0].w;
#pragma unroll
            for (int r = 1; r < RANK; ++r) {
                o.x += tv[r] * b[r].x;
                o.y += tv[r] * b[r].y;
                o.z += tv[r] * b[r].z;
                o.w += tv[r] * b[r].w;
            }
            f32x4 ov;
            ov.x = o.x; ov.y = o.y; ov.z = o.z; ov.w = o.w;
            __builtin_nontemporal_store(ov, &out4[(row0 + m) * DIM4 + i4c]);
        }
    }
}

extern "C" void kernel_launch(void* const* d_in, const int* in_sizes, int n_in,
                              void* d_out, int out_size, void* d_ws, size_t ws_size,
                              hipStream_t stream) {
    const float* x = (const float*)d_in[0];   // [4, 2048, 4096]
    const float* A = (const float*)d_in[1];   // [4096, 8]
    const float* B = (const float*)d_in[2];   // [8, 4096]
    float* out = (float*)d_out;

    const int rows = in_sizes[0] / DIM;       // 8192
    lora_fused_kernel<<<rows / RPB, BLOCK, 0, stream>>>(x, A, B, out);
}

// Round 6
// 344.827 us; speedup vs baseline: 1.0308x; 1.0308x over previous
//
#include <hip/hip_runtime.h>

// LoRA forward: out = x @ (A @ B * scale)  ==  ((x @ A) * scale) @ B
// x: [4, 2048, 4096] fp32 -> 8192 rows; A: [4096, 8]; B: [8, 4096]; out: [8192, 4096]
//
// R6 post-mortem: structure worked (Occ 72%, HBM 3.6 TB/s) but
// launch_bounds(1024,8) forced VGPR=32 -> b[]/xq[] spilled to scratch:
// WRITE_SIZE 473 MB (3.6x output), FETCH +120 MB = pure spill traffic.
// R7: same VMEM-diet structure, spill-free residency:
//  - BLOCK=512 (8 waves), launch_bounds(512,4) -> VGPR cap 128 (~70 needed).
//  - LDS 66 KB -> 2 blocks/CU co-resident (132<=160 KB, 16 waves/CU
//    = 4 waves/SIMD at VGPR<=128); one block covers the other's barriers.
//  - ROWS=2/wave, RPB=16 -> grid 512 = exactly 2/CU, single round, no tail.
//  - Phase 2: predicated per-rank select (NO runtime-indexed acc[] -> no
//    scratch); phase 3: t via 2 uniform ds_read_b128 broadcasts per row.

#define DIM        4096
#define DIM4       1024        // float4 quads per row
#define RANK       8
#define LORA_SCALE 2.0f
#define BLOCK      512
#define WAVES      8
#define ROWS       2           // x-rows per wave
#define RPB        (WAVES * ROWS)  // 16 rows per block
#define HALF_COLS  2048        // scalar columns per LDS half
#define HALF_Q     512         // float4 quads per half per rank-row

typedef float f32x4 __attribute__((ext_vector_type(4)));

__global__ __launch_bounds__(BLOCK, 4) void lora_fused_kernel(
    const float* __restrict__ x,
    const float* __restrict__ A,
    const float* __restrict__ B,
    float* __restrict__ out)
{
    __shared__ float sAt[RANK * HALF_COLS];   // 64 KiB: transposed half of A
    __shared__ float tAll[RPB * RANK];        // 512 B: per-row (x@A)*scale

    const int tid  = threadIdx.x;
    const int wave = tid >> 6;
    const int lane = tid & 63;
    const size_t row0 = (size_t)blockIdx.x * RPB;

    const float4* __restrict__ A4 = (const float4*)A;   // 8192 quads total
    const float4* __restrict__ B4 = (const float4*)B;
    const float4* __restrict__ x4 = (const float4*)x;
    const float4* sAt4 = (const float4*)sAt;

    // ---- Phase 1: acc[m][r] = sum_i x[row][i] * A[i][r], two column halves ----
    float acc[ROWS][RANK];
#pragma unroll
    for (int m = 0; m < ROWS; ++m)
#pragma unroll
        for (int r = 0; r < RANK; ++r) acc[m][r] = 0.f;

    for (int h = 0; h < 2; ++h) {
        if (h) __syncthreads();   // half-0 compute done before overwriting sAt
        // Stage: transpose A rows [h*2048, +2048) (contiguous 64 KB of A) into
        // sAt[r][il]. Global quad idx -> (il = idx>>1, rq = (idx&1)*4).
        // LDS writes: 2 lanes/bank (same il parity, rq 0 vs 4) = free 2-way.
#pragma unroll
        for (int q = 0; q < 8; ++q) {
            const int idx = tid + q * BLOCK;           // 0..4095
            const float4 v = A4[h * 4096 + idx];       // coalesced
            const int il = idx >> 1;                   // local column 0..2047
            const int rq = (idx & 1) * 4;
            sAt[(rq + 0) * HALF_COLS + il] = v.x;
            sAt[(rq + 1) * HALF_COLS + il] = v.y;
            sAt[(rq + 2) * HALF_COLS + il] = v.z;
            sAt[(rq + 3) * HALF_COLS + il] = v.w;
        }
        __syncthreads();

        // Compute this half: 8 quad-positions per lane per row, batch 2 deep.
#pragma unroll
        for (int pb = 0; pb < 4; ++pb) {
            float4 xq[2][ROWS];
#pragma unroll
            for (int j = 0; j < 2; ++j)
#pragma unroll
                for (int m = 0; m < ROWS; ++m)
                    xq[j][m] = x4[(row0 + wave * ROWS + m) * DIM4
                                  + h * HALF_Q + (pb * 2 + j) * 64 + lane];
#pragma unroll
            for (int j = 0; j < 2; ++j) {
                const int il4 = (pb * 2 + j) * 64 + lane;   // 0..511
#pragma unroll
                for (int r = 0; r < RANK; ++r) {
                    const float4 a = sAt4[r * HALF_Q + il4]; // ds_read_b128
#pragma unroll
                    for (int m = 0; m < ROWS; ++m)
                        acc[m][r] += xq[j][m].x * a.x + xq[j][m].y * a.y
                                   + xq[j][m].z * a.z + xq[j][m].w * a.w;
                }
            }
        }
    }

    // ---- Phase 2: butterfly reduce per row; lane<8 deposits t into LDS ----
#pragma unroll
    for (int m = 0; m < ROWS; ++m) {
        float tval = 0.f;
#pragma unroll
        for (int r = 0; r < RANK; ++r) {
            float v = acc[m][r];
#pragma unroll
            for (int off = 1; off < 64; off <<= 1)
                v += __shfl_xor(v, off, 64);
            v *= LORA_SCALE;
            if (lane == r) tval = v;   // predicated select, compile-time r
        }
        if (lane < RANK)
            tAll[(wave * ROWS + m) * RANK + lane] = tval;
    }
    __syncthreads();

    // ---- Phase 3: wave owns column quads; B slice in regs, reused 16 rows ----
    const float4* tAll4 = (const float4*)tAll;
    f32x4* __restrict__ out4 = (f32x4*)out;
#pragma unroll
    for (int h3 = 0; h3 < 2; ++h3) {
        const int i4c = h3 * (WAVES * 64) + wave * 64 + lane;  // 0..1023
        float4 b[RANK];
#pragma unroll
        for (int r = 0; r < RANK; ++r)
            b[r] = B4[r * DIM4 + i4c];                 // coalesced, once per h3
#pragma unroll 4
        for (int m = 0; m < RPB; ++m) {
            const float4 t0 = tAll4[m * 2 + 0];        // uniform: LDS broadcast
            const float4 t1 = tAll4[m * 2 + 1];
            float4 o;
            o.x = t0.x * b[0].x; o.y = t0.x * b[0].y;
            o.z = t0.x * b[0].z; o.w = t0.x * b[0].w;
            o.x += t0.y * b[1].x; o.y += t0.y * b[1].y;
            o.z += t0.y * b[1].z; o.w += t0.y * b[1].w;
            o.x += t0.z * b[2].x; o.y += t0.z * b[2].y;
            o.z += t0.z * b[2].z; o.w += t0.z * b[2].w;
            o.x += t0.w * b[3].x; o.y += t0.w * b[3].y;
            o.z += t0.w * b[3].z; o.w += t0.w * b[3].w;
            o.x += t1.x * b[4].x; o.y += t1.x * b[4].y;
            o.z += t1.x * b[4].z; o.w += t1.x * b[4].w;
            o.x += t1.y * b[5].x; o.y += t1.y * b[5].y;
            o.z += t1.y * b[5].z; o.w += t1.y * b[5].w;
            o.x += t1.z * b[6].x; o.y += t1.z * b[6].y;
            o.z += t1.z * b[6].z; o.w += t1.z * b[6].w;
            o.x += t1.w * b[7].x; o.y += t1.w * b[7].y;
            o.z += t1.w * b[7].z; o.w += t1.w * b[7].w;
            f32x4 ov;
            ov.x = o.x; ov.y = o.y; ov.z = o.z; ov.w = o.w;
            __builtin_nontemporal_store(ov, &out4[(row0 + m) * DIM4 + i4c]);
        }
    }
}

extern "C" void kernel_launch(void* const* d_in, const int* in_sizes, int n_in,
                              void* d_out, int out_size, void* d_ws, size_t ws_size,
                              hipStream_t stream) {
    const float* x = (const float*)d_in[0];   // [4, 2048, 4096]
    const float* A = (const float*)d_in[1];   // [4096, 8]
    const float* B = (const float*)d_in[2];   // [8, 4096]
    float* out = (float*)d_out;

    const int rows = in_sizes[0] / DIM;       // 8192
    lora_fused_kernel<<<rows / RPB, BLOCK, 0, stream>>>(x, A, B, out);
}

// Round 7
// 257.242 us; speedup vs baseline: 1.3818x; 1.3405x over previous
//
#include <hip/hip_runtime.h>

// LoRA forward: out = x @ (A @ B * scale)  ==  ((x @ A) * scale) @ B
// x: [4, 2048, 4096] fp32 -> 8192 rows; A: [4096, 8]; B: [8, 4096]; out: [8192, 4096]
//
// R7 post-mortem: STILL spilling. VGPR=64, WRITE_SIZE=400 MiB (272 MiB
// scratch write-back; scratch reads hit L2 so FETCH only +83 MB).
// Empirical __launch_bounds__ semantics on hipcc here: arg2 = min BLOCKS/CU
// (CUDA semantics). (1024,8)->VGPR 32; (512,4)->VGPR 64. Cap = 512 regs/SIMD
// / (arg2 * waves_per_block / 4).
// R8: __launch_bounds__(512, 2) -> 16 waves/CU -> VGPR cap 128 -> no spill.
// Everything else identical to R7 (isolate the spill fix):
//  - At staged in LDS 64 KB halves (in-block transpose, contiguous A reads).
//  - Block = 8 waves x 2 rows; butterfly reduce; t exchanged via 512 B LDS.
//  - Phase 3: wave owns column quads, B slice in 8 regs reused over 16 rows.
//  - LDS 66 KB -> exactly 2 blocks/CU (132<=160 KB); grid 512 = 2/CU, 1 round.

#define DIM        4096
#define DIM4       1024        // float4 quads per row
#define RANK       8
#define LORA_SCALE 2.0f
#define BLOCK      512
#define WAVES      8
#define ROWS       2           // x-rows per wave
#define RPB        (WAVES * ROWS)  // 16 rows per block
#define HALF_COLS  2048        // scalar columns per LDS half
#define HALF_Q     512         // float4 quads per half per rank-row

typedef float f32x4 __attribute__((ext_vector_type(4)));

__global__ __launch_bounds__(BLOCK, 2) void lora_fused_kernel(
    const float* __restrict__ x,
    const float* __restrict__ A,
    const float* __restrict__ B,
    float* __restrict__ out)
{
    __shared__ float sAt[RANK * HALF_COLS];   // 64 KiB: transposed half of A
    __shared__ float tAll[RPB * RANK];        // 512 B: per-row (x@A)*scale

    const int tid  = threadIdx.x;
    const int wave = tid >> 6;
    const int lane = tid & 63;
    const size_t row0 = (size_t)blockIdx.x * RPB;

    const float4* __restrict__ A4 = (const float4*)A;   // 8192 quads total
    const float4* __restrict__ B4 = (const float4*)B;
    const float4* __restrict__ x4 = (const float4*)x;
    const float4* sAt4 = (const float4*)sAt;

    // ---- Phase 1: acc[m][r] = sum_i x[row][i] * A[i][r], two column halves ----
    float acc[ROWS][RANK];
#pragma unroll
    for (int m = 0; m < ROWS; ++m)
#pragma unroll
        for (int r = 0; r < RANK; ++r) acc[m][r] = 0.f;

    for (int h = 0; h < 2; ++h) {
        if (h) __syncthreads();   // half-0 compute done before overwriting sAt
        // Stage: transpose A rows [h*2048, +2048) (contiguous 64 KB of A) into
        // sAt[r][il]. Global quad idx -> (il = idx>>1, rq = (idx&1)*4).
#pragma unroll
        for (int q = 0; q < 8; ++q) {
            const int idx = tid + q * BLOCK;           // 0..4095
            const float4 v = A4[h * 4096 + idx];       // coalesced
            const int il = idx >> 1;                   // local column 0..2047
            const int rq = (idx & 1) * 4;
            sAt[(rq + 0) * HALF_COLS + il] = v.x;
            sAt[(rq + 1) * HALF_COLS + il] = v.y;
            sAt[(rq + 2) * HALF_COLS + il] = v.z;
            sAt[(rq + 3) * HALF_COLS + il] = v.w;
        }
        __syncthreads();

        // Compute this half: 8 quad-positions per lane per row, batch 2 deep.
#pragma unroll
        for (int pb = 0; pb < 4; ++pb) {
            float4 xq[2][ROWS];
#pragma unroll
            for (int j = 0; j < 2; ++j)
#pragma unroll
                for (int m = 0; m < ROWS; ++m)
                    xq[j][m] = x4[(row0 + wave * ROWS + m) * DIM4
                                  + h * HALF_Q + (pb * 2 + j) * 64 + lane];
#pragma unroll
            for (int j = 0; j < 2; ++j) {
                const int il4 = (pb * 2 + j) * 64 + lane;   // 0..511
#pragma unroll
                for (int r = 0; r < RANK; ++r) {
                    const float4 a = sAt4[r * HALF_Q + il4]; // ds_read_b128
#pragma unroll
                    for (int m = 0; m < ROWS; ++m)
                        acc[m][r] += xq[j][m].x * a.x + xq[j][m].y * a.y
                                   + xq[j][m].z * a.z + xq[j][m].w * a.w;
                }
            }
        }
    }

    // ---- Phase 2: butterfly reduce per row; lane<8 deposits t into LDS ----
#pragma unroll
    for (int m = 0; m < ROWS; ++m) {
        float tval = 0.f;
#pragma unroll
        for (int r = 0; r < RANK; ++r) {
            float v = acc[m][r];
#pragma unroll
            for (int off = 1; off < 64; off <<= 1)
                v += __shfl_xor(v, off, 64);
            v *= LORA_SCALE;
            if (lane == r) tval = v;   // predicated select, compile-time r
        }
        if (lane < RANK)
            tAll[(wave * ROWS + m) * RANK + lane] = tval;
    }
    __syncthreads();

    // ---- Phase 3: wave owns column quads; B slice in regs, reused 16 rows ----
    const float4* tAll4 = (const float4*)tAll;
    f32x4* __restrict__ out4 = (f32x4*)out;
#pragma unroll
    for (int h3 = 0; h3 < 2; ++h3) {
        const int i4c = h3 * (WAVES * 64) + wave * 64 + lane;  // 0..1023
        float4 b[RANK];
#pragma unroll
        for (int r = 0; r < RANK; ++r)
            b[r] = B4[r * DIM4 + i4c];                 // coalesced, once per h3
#pragma unroll 4
        for (int m = 0; m < RPB; ++m) {
            const float4 t0 = tAll4[m * 2 + 0];        // uniform: LDS broadcast
            const float4 t1 = tAll4[m * 2 + 1];
            float4 o;
            o.x = t0.x * b[0].x; o.y = t0.x * b[0].y;
            o.z = t0.x * b[0].z; o.w = t0.x * b[0].w;
            o.x += t0.y * b[1].x; o.y += t0.y * b[1].y;
            o.z += t0.y * b[1].z; o.w += t0.y * b[1].w;
            o.x += t0.z * b[2].x; o.y += t0.z * b[2].y;
            o.z += t0.z * b[2].z; o.w += t0.z * b[2].w;
            o.x += t0.w * b[3].x; o.y += t0.w * b[3].y;
            o.z += t0.w * b[3].z; o.w += t0.w * b[3].w;
            o.x += t1.x * b[4].x; o.y += t1.x * b[4].y;
            o.z += t1.x * b[4].z; o.w += t1.x * b[4].w;
            o.x += t1.y * b[5].x; o.y += t1.y * b[5].y;
            o.z += t1.y * b[5].z; o.w += t1.y * b[5].w;
            o.x += t1.z * b[6].x; o.y += t1.z * b[6].y;
            o.z += t1.z * b[6].z; o.w += t1.z * b[6].w;
            o.x += t1.w * b[7].x; o.y += t1.w * b[7].y;
            o.z += t1.w * b[7].z; o.w += t1.w * b[7].w;
            f32x4 ov;
            ov.x = o.x; ov.y = o.y; ov.z = o.z; ov.w = o.w;
            __builtin_nontemporal_store(ov, &out4[(row0 + m) * DIM4 + i4c]);
        }
    }
}

extern "C" void kernel_launch(void* const* d_in, const int* in_sizes, int n_in,
                              void* d_out, int out_size, void* d_ws, size_t ws_size,
                              hipStream_t stream) {
    const float* x = (const float*)d_in[0];   // [4, 2048, 4096]
    const float* A = (const float*)d_in[1];   // [4096, 8]
    const float* B = (const float*)d_in[2];   // [8, 4096]
    float* out = (float*)d_out;

    const int rows = in_sizes[0] / DIM;       // 8192
    lora_fused_kernel<<<rows / RPB, BLOCK, 0, stream>>>(x, A, B, out);
}

// Round 8
// 243.985 us; speedup vs baseline: 1.4568x; 1.0543x over previous
//
#include <hip/hip_runtime.h>

// LoRA forward: out = x @ (A @ B * scale), split as:
//   Kernel Y: y[8192][8] = scale * (x @ A)     (x-read-bound, 134 MB)
//   Kernel O: out = y @ B                      (out-write-bound, 134 MB)
//
// R8 post-mortem: spill fixed (WRITE 144 MB, VGPR 128) but 100 us at
// 2.3 TB/s, Occ 19%, VALU 13% -> MLP/concurrency-bound: 16 waves/CU with
// shallow per-wave load depth can't fill the memory pipe (copy ubench needs
// ~32 waves/CU + deep pipelines for 6.3 TB/s). Single kernel couples phase-1
// and phase-3 register budgets and barrier-stalls 2 blocks/CU.
// R9: two pure streaming kernels with independent budgets:
//  - Y: LDS-At halves + 4-deep xq prefetch (8 KB in flight/wave), (512,2).
//  - O: NO LDS, NO barriers; B slice in 8 regs reused over 16 rows; t via
//    uniform broadcast loads (y is L2-hot); VGPR ~55 -> 32 waves/CU; XCD
//    swizzle colocates B col-slices per XCD. NT stores.

#define DIM        4096
#define DIM4       1024        // float4 quads per row
#define RANK       8
#define LORA_SCALE 2.0f

typedef float f32x4 __attribute__((ext_vector_type(4)));

// ---------------- Kernel Y: y = scale * (x @ A) ----------------
#define YBLOCK     512
#define YWAVES     8
#define YROWS      2                    // x-rows per wave
#define YRPB       (YWAVES * YROWS)     // 16 rows per block
#define HALF_COLS  2048
#define HALF_Q     512                  // quads per half per rank-row

__global__ __launch_bounds__(YBLOCK, 2) void lora_xa_kernel(
    const float* __restrict__ x,
    const float* __restrict__ A,
    float* __restrict__ y)
{
    __shared__ float sAt[RANK * HALF_COLS];   // 64 KiB

    const int tid  = threadIdx.x;
    const int wave = tid >> 6;
    const int lane = tid & 63;
    const size_t row0 = (size_t)blockIdx.x * YRPB;

    const float4* __restrict__ A4 = (const float4*)A;
    const float4* __restrict__ x4 = (const float4*)x;
    const float4* sAt4 = (const float4*)sAt;

    float acc[YROWS][RANK];
#pragma unroll
    for (int m = 0; m < YROWS; ++m)
#pragma unroll
        for (int r = 0; r < RANK; ++r) acc[m][r] = 0.f;

    for (int h = 0; h < 2; ++h) {
        if (h) __syncthreads();
        // Stage half of A (contiguous 64 KB) transposed into sAt.
#pragma unroll
        for (int q = 0; q < 8; ++q) {
            const int idx = tid + q * YBLOCK;          // 0..4095
            const float4 v = A4[h * 4096 + idx];
            const int il = idx >> 1;
            const int rq = (idx & 1) * 4;
            sAt[(rq + 0) * HALF_COLS + il] = v.x;
            sAt[(rq + 1) * HALF_COLS + il] = v.y;
            sAt[(rq + 2) * HALF_COLS + il] = v.z;
            sAt[(rq + 3) * HALF_COLS + il] = v.w;
        }
        __syncthreads();

        // 8 positions per half; 4-deep x prefetch (8 loads in flight/wave).
#pragma unroll
        for (int pb = 0; pb < 2; ++pb) {
            float4 xq[4][YROWS];
#pragma unroll
            for (int p = 0; p < 4; ++p)
#pragma unroll
                for (int m = 0; m < YROWS; ++m)
                    xq[p][m] = x4[(row0 + wave * YROWS + m) * DIM4
                                  + h * HALF_Q + (pb * 4 + p) * 64 + lane];
#pragma unroll
            for (int p = 0; p < 4; ++p) {
                const int il4 = (pb * 4 + p) * 64 + lane;
#pragma unroll
                for (int r = 0; r < RANK; ++r) {
                    const float4 a = sAt4[r * HALF_Q + il4];
#pragma unroll
                    for (int m = 0; m < YROWS; ++m)
                        acc[m][r] += xq[p][m].x * a.x + xq[p][m].y * a.y
                                   + xq[p][m].z * a.z + xq[p][m].w * a.w;
                }
            }
        }
    }

    // Butterfly reduce per row; lane<8 writes y[row][lane].
#pragma unroll
    for (int m = 0; m < YROWS; ++m) {
        float tval = 0.f;
#pragma unroll
        for (int r = 0; r < RANK; ++r) {
            float v = acc[m][r];
#pragma unroll
            for (int off = 1; off < 64; off <<= 1)
                v += __shfl_xor(v, off, 64);
            v *= LORA_SCALE;
            if (lane == r) tval = v;
        }
        if (lane < RANK)
            y[(row0 + wave * YROWS + m) * RANK + lane] = tval;
    }
}

// ---------------- Kernel O: out = y @ B ----------------
#define OBLOCK     256
#define OWAVES     4
#define OROWS      16          // rows per block
#define OCOLQ      256         // col-quads per block (= 1024 cols)

__global__ __launch_bounds__(OBLOCK, 6) void lora_yb_kernel(
    const float* __restrict__ y,
    const float* __restrict__ B,
    float* __restrict__ out)
{
    // XCD swizzle: grid = 2048 = 4 colblks x 512 rowblks. Perfect-shuffle
    // remap gives each XCD one B col-slice (32 KB) + 256 contiguous rowblks.
    const int swz    = (blockIdx.x & 7) * 256 + (blockIdx.x >> 3);
    const int colblk = swz >> 9;          // 0..3
    const int rowblk = swz & 511;         // 0..511

    const int tid  = threadIdx.x;
    const int wave = tid >> 6;
    const int lane = tid & 63;
    const size_t row0 = (size_t)rowblk * OROWS;
    const int i4c = colblk * OCOLQ + wave * 64 + lane;   // 0..1023

    const float4* __restrict__ B4 = (const float4*)B;
    const float4* __restrict__ y4 = (const float4*)y;    // y[row] = 2 quads
    f32x4* __restrict__ out4 = (f32x4*)out;

    float4 b[RANK];
#pragma unroll
    for (int r = 0; r < RANK; ++r)
        b[r] = B4[r * DIM4 + i4c];        // coalesced; L2-hot after first touch

#pragma unroll 4
    for (int m = 0; m < OROWS; ++m) {
        const float4 t0 = y4[(row0 + m) * 2 + 0];   // uniform -> broadcast
        const float4 t1 = y4[(row0 + m) * 2 + 1];
        float4 o;
        o.x = t0.x * b[0].x; o.y = t0.x * b[0].y;
        o.z = t0.x * b[0].z; o.w = t0.x * b[0].w;
        o.x += t0.y * b[1].x; o.y += t0.y * b[1].y;
        o.z += t0.y * b[1].z; o.w += t0.y * b[1].w;
        o.x += t0.z * b[2].x; o.y += t0.z * b[2].y;
        o.z += t0.z * b[2].z; o.w += t0.z * b[2].w;
        o.x += t0.w * b[3].x; o.y += t0.w * b[3].y;
        o.z += t0.w * b[3].z; o.w += t0.w * b[3].w;
        o.x += t1.x * b[4].x; o.y += t1.x * b[4].y;
        o.z += t1.x * b[4].z; o.w += t1.x * b[4].w;
        o.x += t1.y * b[5].x; o.y += t1.y * b[5].y;
        o.z += t1.y * b[5].z; o.w += t1.y * b[5].w;
        o.x += t1.z * b[6].x; o.y += t1.z * b[6].y;
        o.z += t1.z * b[6].z; o.w += t1.z * b[6].w;
        o.x += t1.w * b[7].x; o.y += t1.w * b[7].y;
        o.z += t1.w * b[7].z; o.w += t1.w * b[7].w;
        f32x4 ov;
        ov.x = o.x; ov.y = o.y; ov.z = o.z; ov.w = o.w;
        __builtin_nontemporal_store(ov, &out4[(row0 + m) * DIM4 + i4c]);
    }
}

extern "C" void kernel_launch(void* const* d_in, const int* in_sizes, int n_in,
                              void* d_out, int out_size, void* d_ws, size_t ws_size,
                              hipStream_t stream) {
    const float* x = (const float*)d_in[0];   // [4, 2048, 4096]
    const float* A = (const float*)d_in[1];   // [4096, 8]
    const float* B = (const float*)d_in[2];   // [8, 4096]
    float* out = (float*)d_out;
    float* y   = (float*)d_ws;                // 8192*8 floats = 256 KiB

    const int rows = in_sizes[0] / DIM;       // 8192

    lora_xa_kernel<<<rows / YRPB, YBLOCK, 0, stream>>>(x, A, y);
    lora_yb_kernel<<<(rows / OROWS) * (DIM4 / OCOLQ), OBLOCK, 0, stream>>>(y, B, out);
}